// Round 3
// baseline (557.861 us; speedup 1.0000x reference)
//
#include <hip/hip_runtime.h>
#include <hip/hip_bf16.h>

#define BB 64
#define TT 1024
#define DD 512
#define NS 24

#define POT_OFF   65536
#define LENS_OFF  1638400
#define TRANS_OFF 1638464

// ---------------------------------------------------------------------------
// Kernel 1: pot = x @ W + b (+ boundary adds).  (byte-identical this round —
// kept fixed so the viterbi delta is attributable; if it now shows in the
// top-5 we get its counters next round.)
// ---------------------------------------------------------------------------
__global__ __launch_bounds__(256) void gemm_pot(
    const float* __restrict__ x, const float* __restrict__ W,
    const float* __restrict__ bias, const float* __restrict__ trans,
    const float* __restrict__ lb, const float* __restrict__ rb,
    float* __restrict__ out)
{
  __shared__ float wl[DD * NS];              // 49,152 B: W, then partials
  const int tid = threadIdx.x;
  const int l   = tid & 63;
  const int q   = tid >> 6;                  // K-quarter
  const int row = blockIdx.x * 64 + l;

  // stage W: 12288 floats = 256 threads x 12 float4, coalesced
  {
    const float4* Ws = (const float4*)W;
    float4* Wd = (float4*)wl;
#pragma unroll
    for (int i = 0; i < 12; ++i) Wd[tid + i * 256] = Ws[tid + i * 256];
  }
  __syncthreads();

  const float4* xp = (const float4*)(x + (size_t)row * DD + q * 128);

  float acc[NS];
#pragma unroll
  for (int nn = 0; nn < NS; ++nn) acc[nn] = 0.f;

  float4 buf[8];
#pragma unroll
  for (int i = 0; i < 8; ++i) buf[i] = xp[i];

#pragma unroll
  for (int f = 0; f < 32; ++f) {             // 32 float4 = 128 k per quarter
    float4 v = buf[f & 7];
    if (f + 8 < 32) buf[f & 7] = xp[f + 8];  // refill window
    const float xj[4] = {v.x, v.y, v.z, v.w};
#pragma unroll
    for (int j = 0; j < 4; ++j) {
      const int k = q * 128 + f * 4 + j;
      const float4* wr = (const float4*)&wl[k * NS];   // same addr all lanes
      float4 w0 = wr[0], w1 = wr[1], w2 = wr[2], w3 = wr[3], w4 = wr[4], w5 = wr[5];
      const float wv[NS] = {w0.x,w0.y,w0.z,w0.w, w1.x,w1.y,w1.z,w1.w,
                            w2.x,w2.y,w2.z,w2.w, w3.x,w3.y,w3.z,w3.w,
                            w4.x,w4.y,w4.z,w4.w, w5.x,w5.y,w5.z,w5.w};
      const float xv = xj[j];
#pragma unroll
      for (int nn = 0; nn < NS; ++nn) acc[nn] = fmaf(xv, wv[nn], acc[nn]);
    }
  }

  // reduce the 4 K-quarter partials through W's (now dead) LDS region
  __syncthreads();
  if (q != 0) {
#pragma unroll
    for (int nn = 0; nn < NS; ++nn) wl[((q - 1) * 64 + l) * 25 + nn] = acc[nn];
  }
  __syncthreads();
  if (q == 0) {
    const int t = row & (TT - 1);
#pragma unroll
    for (int nn = 0; nn < NS; ++nn)
      acc[nn] += wl[(0 * 64 + l) * 25 + nn] + wl[(1 * 64 + l) * 25 + nn]
               + wl[(2 * 64 + l) * 25 + nn] + bias[nn];
    if (t == 0) {
#pragma unroll
      for (int nn = 0; nn < NS; ++nn) acc[nn] += lb[nn];
    }
    if (t == TT - 1) {
#pragma unroll
      for (int nn = 0; nn < NS; ++nn) acc[nn] += rb[nn];
    }
    float* po = out + POT_OFF + (size_t)row * NS;
#pragma unroll
    for (int i = 0; i < 6; ++i)
      *(float4*)(po + i * 4) = make_float4(acc[4*i], acc[4*i+1], acc[4*i+2], acc[4*i+3]);
  }

  if (blockIdx.x == 0 && tid < BB) out[LENS_OFF + tid] = (float)TT;
  if (blockIdx.x == 1) {
    for (int i = tid; i < NS * NS; i += 256) out[TRANS_OFF + i] = trans[i];
  }
}

__device__ __forceinline__ float m3(float a, float b, float c) {
  return fmaxf(fmaxf(a, b), c);   // clang fuses to v_max3_f32
}

// ---------------------------------------------------------------------------
// Kernel 2 (fused): scan + bp + backtrace, one block per batch, 1024 threads.
// Scan: m-split over wave halves. Lane (h = tid>>5, n = tid&31 clamped)
// holds alpha[12h+m] (m=0..11) and reduces its half: 12 add + 6-op max3
// tree + add pot -> y_h[n]. Exact: max(pm0,pm1)+pot == max(pm0+pot,pm1+pot)
// (rounding is monotone). Redistribution = 24 PARALLEL ds_bpermute of y
// (register crossbar, no LDS memory round-trip) + 12 in-lane max -> next
// alphas. Chain has exactly ONE bpermute latency; readlane (SGPR hazards,
// r1: 345cy/step) and LDS write->readback (r0: 298cy/step) both eliminated.
// Alpha row still ds_write'n (off-chain, bpermute-combined) for bp-build.
// ---------------------------------------------------------------------------
__global__ __launch_bounds__(1024) void viterbi_fused(
    const float* __restrict__ pot, const float* __restrict__ trans,
    float* __restrict__ out_dec)
{
  __shared__ float ps[(TT + 8) * NS];     // pot rows, overwritten by alpha
  __shared__ unsigned char bl[TT * NS];   // backpointers
  __shared__ float tl[NS * NS];           // trans
  __shared__ int H[32][NS];
  __shared__ int e[32];

  const int b = blockIdx.x, tid = threadIdx.x;

  // ---- stage pot[b] + trans ----
  {
    const float4* src = (const float4*)(pot + (size_t)b * TT * NS);
    float4* dst = (float4*)ps;
#pragma unroll
    for (int i = 0; i < 6; ++i) dst[tid + i * 1024] = src[tid + i * 1024];
    if (tid < NS * NS) tl[tid] = trans[tid];
  }
  __syncthreads();

  // ---- forward scan: wave 0 only ----
  if (tid < 64) {
    const int h  = tid >> 5;               // m-half 0/1
    const int n0 = tid & 31;
    const int n  = (n0 < 24) ? n0 : 23;    // clamped lanes duplicate n=23

    float tc[12];                          // T[12h+m][n]
#pragma unroll
    for (int m = 0; m < 12; ++m) tc[m] = tl[(12 * h + m) * NS + n];

    // init a[m] = alpha0[12h+m] = pot row 0 (b128 broadcast, 48h is 16B-aligned)
    float a[12];
    {
      const float4* rr = (const float4*)&ps[12 * h];
#pragma unroll
      for (int i = 0; i < 3; ++i) {
        float4 v = rr[i];
        a[4*i] = v.x; a[4*i+1] = v.y; a[4*i+2] = v.z; a[4*i+3] = v.w;
      }
    }

    // bpermute byte addresses (per-lane constants, unrolled-static arrays)
    int au[12], av[12];
#pragma unroll
    for (int m = 0; m < 12; ++m) {
      au[m] = (12 * h + m) * 4;            // y_0[12h+m] lives at lane 12h+m
      av[m] = (32 + 12 * h + m) * 4;       // y_1[12h+m] lives at lane 32+12h+m
    }
    const int ap = (tid ^ 32) * 4;         // partner half, same n

    float pv[8];                           // pot prefetch ring (off-chain)
#pragma unroll
    for (int u = 0; u < 8; ++u) pv[u] = ps[(1 + u) * NS + n];

    auto step = [&](int tt, float potv) {
      float sc[12];
#pragma unroll
      for (int m = 0; m < 12; ++m) sc[m] = a[m] + tc[m];
      float v0 = m3(sc[0], sc[1],  sc[2]);
      float v1 = m3(sc[3], sc[4],  sc[5]);
      float v2 = m3(sc[6], sc[7],  sc[8]);
      float v3 = m3(sc[9], sc[10], sc[11]);
      float pm = fmaxf(m3(v0, v1, v2), v3);
      float y  = pm + potv;                // y_h[n]
      const int yi = __float_as_int(y);

      // redistribute (chain-critical): fetch both halves' y at m-slots, max
#pragma unroll
      for (int m = 0; m < 12; ++m) {
        int um = __builtin_amdgcn_ds_bpermute(au[m], yi);
        int vm = __builtin_amdgcn_ds_bpermute(av[m], yi);
        a[m] = fmaxf(__int_as_float(um), __int_as_float(vm));
      }

      // off-chain: combine across halves and store alpha row for bp-build
      int w = __builtin_amdgcn_ds_bpermute(ap, yi);
      float an = fmaxf(y, __int_as_float(w));
      ps[tt * NS + n] = an;                // dup lanes write same value/addr
    };

    for (int t = 1; t + 7 <= TT - 1; t += 8) {
#pragma unroll
      for (int u = 0; u < 8; ++u) {
        const int tt = t + u;
        const float potv = pv[u];
        pv[u] = ps[(tt + 8) * NS + n];     // 8 ahead of overwrite frontier
        step(tt, potv);
      }
    }
#pragma unroll
    for (int u = 0; u < 7; ++u) step(1017 + u, pv[u]);
  }
  __syncthreads();

  // ---- bp build from LDS alphas (bit-exact, first-max strict >) ----
  for (int idx = tid; idx < (TT - 1) * NS; idx += 1024) {
    const int n = idx % NS;
    const int t = idx / NS + 1;
    const float* ar = &ps[(t - 1) * NS];
    float best = ar[0] + tl[n];
    int bi = 0;
#pragma unroll
    for (int m = 1; m < NS; ++m) {
      float s = ar[m] + tl[m * NS + n];
      bool g = s > best;
      bi = g ? m : bi;
      best = g ? s : best;
    }
    bl[t * NS + n] = (unsigned char)bi;
  }
  __syncthreads();

  // ---- backtrace: chunk composition (C=32) ----
  if (tid < 32 * NS) {
    const int c = tid / NS, s = tid % NS;
    int a2 = s;
    int tlo = c * 32; if (tlo < 1) tlo = 1;
    for (int t = c * 32 + 31; t >= tlo; --t) a2 = bl[t * NS + a2];
    H[c][s] = a2;
  }
  __syncthreads();

  if (tid == 0) {
    const float* ar = &ps[(TT - 1) * NS];
    float best = ar[0]; int bi = 0;
#pragma unroll
    for (int nn = 1; nn < NS; ++nn) {
      float v = ar[nn];
      if (v > best) { best = v; bi = nn; }
    }
    int tag = bi;
    e[31] = tag;
    for (int c = 31; c >= 1; --c) { tag = H[c][tag]; e[c - 1] = tag; }
  }
  __syncthreads();

  if (tid < 32) {
    const int c = tid;
    int tag = e[c];
    float* od = out_dec + (size_t)b * TT;
    od[c * 32 + 31] = (float)tag;
    for (int t = c * 32 + 30; t >= c * 32; --t) {
      tag = bl[(t + 1) * NS + tag];
      od[t] = (float)tag;
    }
  }
}

// ---------------------------------------------------------------------------
extern "C" void kernel_launch(void* const* d_in, const int* in_sizes, int n_in,
                              void* d_out, int out_size, void* d_ws, size_t ws_size,
                              hipStream_t stream)
{
  const float* x     = (const float*)d_in[0];
  const float* W     = (const float*)d_in[1];
  const float* bias  = (const float*)d_in[2];
  const float* trans = (const float*)d_in[3];
  const float* lb    = (const float*)d_in[4];
  const float* rb    = (const float*)d_in[5];
  float* out = (float*)d_out;

  gemm_pot<<<1024, 256, 0, stream>>>(x, W, bias, trans, lb, rb, out);
  viterbi_fused<<<BB, 1024, 0, stream>>>(out + POT_OFF, trans, out);
}

// Round 4
// 326.967 us; speedup vs baseline: 1.7062x; 1.7062x over previous
//
#include <hip/hip_runtime.h>
#include <hip/hip_bf16.h>

#define BB 64
#define TT 1024
#define DD 512
#define NS 24

#define POT_OFF   65536
#define LENS_OFF  1638400
#define TRANS_OFF 1638464

// ---------------------------------------------------------------------------
// Kernel 1: pot = x @ W + b (+ boundary adds).  (byte-identical again —
// attribution: this round only touches the viterbi scan.)
// ---------------------------------------------------------------------------
__global__ __launch_bounds__(256) void gemm_pot(
    const float* __restrict__ x, const float* __restrict__ W,
    const float* __restrict__ bias, const float* __restrict__ trans,
    const float* __restrict__ lb, const float* __restrict__ rb,
    float* __restrict__ out)
{
  __shared__ float wl[DD * NS];              // 49,152 B: W, then partials
  const int tid = threadIdx.x;
  const int l   = tid & 63;
  const int q   = tid >> 6;                  // K-quarter
  const int row = blockIdx.x * 64 + l;

  // stage W: 12288 floats = 256 threads x 12 float4, coalesced
  {
    const float4* Ws = (const float4*)W;
    float4* Wd = (float4*)wl;
#pragma unroll
    for (int i = 0; i < 12; ++i) Wd[tid + i * 256] = Ws[tid + i * 256];
  }
  __syncthreads();

  const float4* xp = (const float4*)(x + (size_t)row * DD + q * 128);

  float acc[NS];
#pragma unroll
  for (int nn = 0; nn < NS; ++nn) acc[nn] = 0.f;

  float4 buf[8];
#pragma unroll
  for (int i = 0; i < 8; ++i) buf[i] = xp[i];

#pragma unroll
  for (int f = 0; f < 32; ++f) {             // 32 float4 = 128 k per quarter
    float4 v = buf[f & 7];
    if (f + 8 < 32) buf[f & 7] = xp[f + 8];  // refill window
    const float xj[4] = {v.x, v.y, v.z, v.w};
#pragma unroll
    for (int j = 0; j < 4; ++j) {
      const int k = q * 128 + f * 4 + j;
      const float4* wr = (const float4*)&wl[k * NS];   // same addr all lanes
      float4 w0 = wr[0], w1 = wr[1], w2 = wr[2], w3 = wr[3], w4 = wr[4], w5 = wr[5];
      const float wv[NS] = {w0.x,w0.y,w0.z,w0.w, w1.x,w1.y,w1.z,w1.w,
                            w2.x,w2.y,w2.z,w2.w, w3.x,w3.y,w3.z,w3.w,
                            w4.x,w4.y,w4.z,w4.w, w5.x,w5.y,w5.z,w5.w};
      const float xv = xj[j];
#pragma unroll
      for (int nn = 0; nn < NS; ++nn) acc[nn] = fmaf(xv, wv[nn], acc[nn]);
    }
  }

  // reduce the 4 K-quarter partials through W's (now dead) LDS region
  __syncthreads();
  if (q != 0) {
#pragma unroll
    for (int nn = 0; nn < NS; ++nn) wl[((q - 1) * 64 + l) * 25 + nn] = acc[nn];
  }
  __syncthreads();
  if (q == 0) {
    const int t = row & (TT - 1);
#pragma unroll
    for (int nn = 0; nn < NS; ++nn)
      acc[nn] += wl[(0 * 64 + l) * 25 + nn] + wl[(1 * 64 + l) * 25 + nn]
               + wl[(2 * 64 + l) * 25 + nn] + bias[nn];
    if (t == 0) {
#pragma unroll
      for (int nn = 0; nn < NS; ++nn) acc[nn] += lb[nn];
    }
    if (t == TT - 1) {
#pragma unroll
      for (int nn = 0; nn < NS; ++nn) acc[nn] += rb[nn];
    }
    float* po = out + POT_OFF + (size_t)row * NS;
#pragma unroll
    for (int i = 0; i < 6; ++i)
      *(float4*)(po + i * 4) = make_float4(acc[4*i], acc[4*i+1], acc[4*i+2], acc[4*i+3]);
  }

  if (blockIdx.x == 0 && tid < BB) out[LENS_OFF + tid] = (float)TT;
  if (blockIdx.x == 1) {
    for (int i = tid; i < NS * NS; i += 256) out[TRANS_OFF + i] = trans[i];
  }
}

__device__ __forceinline__ float m3(float a, float b, float c) {
  return fmaxf(fmaxf(a, b), c);   // clang fuses to v_max3_f32
}

// DPP row rotate (within 16-lane rows); direction handled by runtime probe.
#define RORI(dst, src, J) \
  dst = __builtin_amdgcn_mov_dpp((src), 0x120 + (J), 0xF, 0xF, true)

// ---------------------------------------------------------------------------
// Kernel 2 (fused): scan + bp + backtrace, one block per batch, 1024 threads.
// Scan: VALU-ONLY cross-lane. Lane (r=l>>4, c=l&15): tag n=16*(r&1)+c
// (24 tags padded to 32), m-half g=r>>1 (pads get tc=-inf). Per step:
// 16 add + 8-op max3 tree (half-max) -> permlane32_swap + max (full max,
// exact) -> +pot (bit-identical alphas) -> masked ds_write (off-chain)
// -> permlane16_swap + cndmask (pick needed alpha half) -> 15 DPP row_ror
// (gather the 16 alphas in-register). Zero DS/SGPR ops on the chain.
// DPP direction + permlane16 result order are derived AT RUNTIME (colv/selx
// probes), so correctness is independent of rotate-direction semantics.
// Measured cost model: DS op ~31cy each single-wave (r2: 838cy/step),
// r0 write->readback 298cy/step; this design ~46 VALU ~100cy/step.
// ---------------------------------------------------------------------------
__global__ __launch_bounds__(1024) void viterbi_fused(
    const float* __restrict__ pot, const float* __restrict__ trans,
    float* __restrict__ out_dec)
{
  __shared__ float ps[(TT + 8) * NS];     // pot rows, overwritten by alpha
  __shared__ unsigned char bl[TT * NS];   // backpointers
  __shared__ float tl[NS * NS];           // trans
  __shared__ int H[32][NS];
  __shared__ int e[32];

  const int b = blockIdx.x, tid = threadIdx.x;

  // ---- stage pot[b] + trans ----
  {
    const float4* src = (const float4*)(pot + (size_t)b * TT * NS);
    float4* dst = (float4*)ps;
#pragma unroll
    for (int i = 0; i < 6; ++i) dst[tid + i * 1024] = src[tid + i * 1024];
    if (tid < NS * NS) tl[tid] = trans[tid];
  }
  __syncthreads();

  // ---- forward scan: wave 0 only ----
  if (tid < 64) {
    const int r = tid >> 4;                // lane row 0..3
    const int c = tid & 15;                // lane col 0..15
    const int g = r >> 1;                  // m-half 0/1
    const int n = 16 * (r & 1) + c;        // tag (valid if < 24)
    const int nm = (n < NS) ? n : (NS - 1);
    const bool wr = (n < NS) && (g == 0);  // unique alpha writers

    // runtime probe: colv[j] = source column of DPP slot j (direction-proof)
    int colv[16];
    colv[0] = c;
    RORI(colv[1],  c, 1);  RORI(colv[2],  c, 2);  RORI(colv[3],  c, 3);
    RORI(colv[4],  c, 4);  RORI(colv[5],  c, 5);  RORI(colv[6],  c, 6);
    RORI(colv[7],  c, 7);  RORI(colv[8],  c, 8);  RORI(colv[9],  c, 9);
    RORI(colv[10], c, 10); RORI(colv[11], c, 11); RORI(colv[12], c, 12);
    RORI(colv[13], c, 13); RORI(colv[14], c, 14); RORI(colv[15], c, 15);

    // runtime probe: which permlane16_swap result holds alpha[16g + c]
    bool selx;
    {
      auto nr = __builtin_amdgcn_permlane16_swap(n, n, false, false);
      selx = (nr[0] == 16 * g + c);
    }

    // per-lane trans constants: slot j pairs with alpha[16g + colv[j]]
    float tcr[16];
#pragma unroll
    for (int j = 0; j < 16; ++j) {
      const int m = 16 * g + colv[j];
      tcr[j] = (m < NS) ? tl[m * NS + nm] : -__builtin_inff();
    }

    // init: slot j holds alpha0[16g + colv[j]] (alpha0 = pot row 0)
    float ar[16];
#pragma unroll
    for (int j = 0; j < 16; ++j) {
      const int m = 16 * g + colv[j];
      ar[j] = ps[(m < NS) ? m : (NS - 1)];
    }

    float pv[8];                           // pot prefetch ring (off-chain)
#pragma unroll
    for (int u = 0; u < 8; ++u) pv[u] = ps[(1 + u) * NS + nm];

    auto step = [&](int tt, float potv) {
      float sc[16];
#pragma unroll
      for (int j = 0; j < 16; ++j) sc[j] = ar[j] + tcr[j];
      float u0 = m3(sc[0],  sc[1],  sc[2]);
      float u1 = m3(sc[3],  sc[4],  sc[5]);
      float u2 = m3(sc[6],  sc[7],  sc[8]);
      float u3 = m3(sc[9],  sc[10], sc[11]);
      float u4 = m3(sc[12], sc[13], sc[14]);
      float pm = fmaxf(m3(u0, u1, u2), m3(u3, u4, sc[15]));   // half-max
      // cross-half combine: one permlane32_swap, results = {own, lane^32}
      auto pr = __builtin_amdgcn_permlane32_swap(
          __float_as_int(pm), __float_as_int(pm), false, false);
      float al = fmaxf(__int_as_float(pr[0]), __int_as_float(pr[1])) + potv;
      if (wr) ps[tt * NS + n] = al;        // off-chain, for bp-build
      // fetch row-partner's alpha; select the half this lane reduces
      auto qr = __builtin_amdgcn_permlane16_swap(
          __float_as_int(al), __float_as_int(al), false, false);
      int asel = selx ? qr[0] : qr[1];     // alpha[16g + c]
      ar[0] = __int_as_float(asel);
      int d1, d2, d3, d4, d5, d6, d7, d8, d9, d10, d11, d12, d13, d14, d15;
      RORI(d1,  asel, 1);  ar[1]  = __int_as_float(d1);
      RORI(d2,  asel, 2);  ar[2]  = __int_as_float(d2);
      RORI(d3,  asel, 3);  ar[3]  = __int_as_float(d3);
      RORI(d4,  asel, 4);  ar[4]  = __int_as_float(d4);
      RORI(d5,  asel, 5);  ar[5]  = __int_as_float(d5);
      RORI(d6,  asel, 6);  ar[6]  = __int_as_float(d6);
      RORI(d7,  asel, 7);  ar[7]  = __int_as_float(d7);
      RORI(d8,  asel, 8);  ar[8]  = __int_as_float(d8);
      RORI(d9,  asel, 9);  ar[9]  = __int_as_float(d9);
      RORI(d10, asel, 10); ar[10] = __int_as_float(d10);
      RORI(d11, asel, 11); ar[11] = __int_as_float(d11);
      RORI(d12, asel, 12); ar[12] = __int_as_float(d12);
      RORI(d13, asel, 13); ar[13] = __int_as_float(d13);
      RORI(d14, asel, 14); ar[14] = __int_as_float(d14);
      RORI(d15, asel, 15); ar[15] = __int_as_float(d15);
    };

    for (int t = 1; t + 7 <= TT - 1; t += 8) {
#pragma unroll
      for (int u = 0; u < 8; ++u) {
        const int tt = t + u;
        const float potv = pv[u];
        pv[u] = ps[(tt + 8) * NS + nm];    // 8 ahead of overwrite frontier
        step(tt, potv);
      }
    }
#pragma unroll
    for (int u = 0; u < 7; ++u) step(1017 + u, pv[u]);
  }
  __syncthreads();

  // ---- bp build from LDS alphas (bit-exact, first-max strict >) ----
  for (int idx = tid; idx < (TT - 1) * NS; idx += 1024) {
    const int n = idx % NS;
    const int t = idx / NS + 1;
    const float* ar = &ps[(t - 1) * NS];
    float best = ar[0] + tl[n];
    int bi = 0;
#pragma unroll
    for (int m = 1; m < NS; ++m) {
      float s = ar[m] + tl[m * NS + n];
      bool gg = s > best;
      bi = gg ? m : bi;
      best = gg ? s : best;
    }
    bl[t * NS + n] = (unsigned char)bi;
  }
  __syncthreads();

  // ---- backtrace: chunk composition (C=32) ----
  if (tid < 32 * NS) {
    const int c2 = tid / NS, s = tid % NS;
    int a2 = s;
    int tlo = c2 * 32; if (tlo < 1) tlo = 1;
    for (int t = c2 * 32 + 31; t >= tlo; --t) a2 = bl[t * NS + a2];
    H[c2][s] = a2;
  }
  __syncthreads();

  if (tid == 0) {
    const float* ar = &ps[(TT - 1) * NS];
    float best = ar[0]; int bi = 0;
#pragma unroll
    for (int nn = 1; nn < NS; ++nn) {
      float v = ar[nn];
      if (v > best) { best = v; bi = nn; }
    }
    int tag = bi;
    e[31] = tag;
    for (int c2 = 31; c2 >= 1; --c2) { tag = H[c2][tag]; e[c2 - 1] = tag; }
  }
  __syncthreads();

  if (tid < 32) {
    const int c2 = tid;
    int tag = e[c2];
    float* od = out_dec + (size_t)b * TT;
    od[c2 * 32 + 31] = (float)tag;
    for (int t = c2 * 32 + 30; t >= c2 * 32; --t) {
      tag = bl[(t + 1) * NS + tag];
      od[t] = (float)tag;
    }
  }
}

// ---------------------------------------------------------------------------
extern "C" void kernel_launch(void* const* d_in, const int* in_sizes, int n_in,
                              void* d_out, int out_size, void* d_ws, size_t ws_size,
                              hipStream_t stream)
{
  const float* x     = (const float*)d_in[0];
  const float* W     = (const float*)d_in[1];
  const float* bias  = (const float*)d_in[2];
  const float* trans = (const float*)d_in[3];
  const float* lb    = (const float*)d_in[4];
  const float* rb    = (const float*)d_in[5];
  float* out = (float*)d_out;

  gemm_pot<<<1024, 256, 0, stream>>>(x, W, bias, trans, lb, rb, out);
  viterbi_fused<<<BB, 1024, 0, stream>>>(out + POT_OFF, trans, out);
}

// Round 5
// 321.701 us; speedup vs baseline: 1.7341x; 1.0164x over previous
//
#include <hip/hip_runtime.h>
#include <hip/hip_bf16.h>

#define BB 64
#define TT 1024
#define DD 512
#define NS 24

#define POT_OFF   65536
#define LENS_OFF  1638400
#define TRANS_OFF 1638464

// ---------------------------------------------------------------------------
// Kernel 1: pot = x @ W + b (+ boundary adds).
// 2 ROWS PER THREAD (512 blocks): the W broadcast reads from LDS (6 b128/k,
// the dominant cost: DS pipe) are amortized over two rows' FMAs -> LDS
// cycles per output halved. Per-row k-order and 4-quarter reduction tree
// identical to the passing version -> pot bit-identical.
// ---------------------------------------------------------------------------
__global__ __launch_bounds__(256) void gemm_pot(
    const float* __restrict__ x, const float* __restrict__ W,
    const float* __restrict__ bias, const float* __restrict__ trans,
    const float* __restrict__ lb, const float* __restrict__ rb,
    float* __restrict__ out)
{
  __shared__ float wl[DD * NS];              // 49,152 B: W, then partials
  const int tid = threadIdx.x;
  const int l   = tid & 63;
  const int q   = tid >> 6;                  // K-quarter
  const int row0 = blockIdx.x * 128 + l;     // this thread's two rows
  const int row1 = row0 + 64;

  // stage W: 12288 floats = 256 threads x 12 float4, coalesced
  {
    const float4* Ws = (const float4*)W;
    float4* Wd = (float4*)wl;
#pragma unroll
    for (int i = 0; i < 12; ++i) Wd[tid + i * 256] = Ws[tid + i * 256];
  }
  __syncthreads();

  const float4* xp0 = (const float4*)(x + (size_t)row0 * DD + q * 128);
  const float4* xp1 = (const float4*)(x + (size_t)row1 * DD + q * 128);

  float acc0[NS], acc1[NS];
#pragma unroll
  for (int nn = 0; nn < NS; ++nn) { acc0[nn] = 0.f; acc1[nn] = 0.f; }

  float4 buf0[4], buf1[4];
#pragma unroll
  for (int i = 0; i < 4; ++i) { buf0[i] = xp0[i]; buf1[i] = xp1[i]; }

#pragma unroll
  for (int f = 0; f < 32; ++f) {             // 32 float4 = 128 k per quarter
    float4 v0 = buf0[f & 3];
    float4 v1 = buf1[f & 3];
    if (f + 4 < 32) { buf0[f & 3] = xp0[f + 4]; buf1[f & 3] = xp1[f + 4]; }
    const float xj0[4] = {v0.x, v0.y, v0.z, v0.w};
    const float xj1[4] = {v1.x, v1.y, v1.z, v1.w};
#pragma unroll
    for (int j = 0; j < 4; ++j) {
      const int k = q * 128 + f * 4 + j;
      const float4* wr = (const float4*)&wl[k * NS];   // same addr all lanes
      float4 w0 = wr[0], w1 = wr[1], w2 = wr[2], w3 = wr[3], w4 = wr[4], w5 = wr[5];
      const float wv[NS] = {w0.x,w0.y,w0.z,w0.w, w1.x,w1.y,w1.z,w1.w,
                            w2.x,w2.y,w2.z,w2.w, w3.x,w3.y,w3.z,w3.w,
                            w4.x,w4.y,w4.z,w4.w, w5.x,w5.y,w5.z,w5.w};
      const float xv0 = xj0[j];
      const float xv1 = xj1[j];
#pragma unroll
      for (int nn = 0; nn < NS; ++nn) {
        acc0[nn] = fmaf(xv0, wv[nn], acc0[nn]);
        acc1[nn] = fmaf(xv1, wv[nn], acc1[nn]);
      }
    }
  }

  // reduce the 4 K-quarter partials through W's (now dead) LDS region
  // slots: (q-1)*128 + {l, 64+l}, stride 25 (odd -> conflict-free)
  __syncthreads();
  if (q != 0) {
#pragma unroll
    for (int nn = 0; nn < NS; ++nn) {
      wl[((q - 1) * 128 + l)      * 25 + nn] = acc0[nn];
      wl[((q - 1) * 128 + 64 + l) * 25 + nn] = acc1[nn];
    }
  }
  __syncthreads();
  if (q == 0) {
#pragma unroll
    for (int rr = 0; rr < 2; ++rr) {
      float* acc = rr ? acc1 : acc0;
      const int row = rr ? row1 : row0;
      const int slot = rr ? (64 + l) : l;
      const int t = row & (TT - 1);
#pragma unroll
      for (int nn = 0; nn < NS; ++nn)
        acc[nn] += wl[(0 * 128 + slot) * 25 + nn] + wl[(1 * 128 + slot) * 25 + nn]
                 + wl[(2 * 128 + slot) * 25 + nn] + bias[nn];
      if (t == 0) {
#pragma unroll
        for (int nn = 0; nn < NS; ++nn) acc[nn] += lb[nn];
      }
      if (t == TT - 1) {
#pragma unroll
        for (int nn = 0; nn < NS; ++nn) acc[nn] += rb[nn];
      }
      float* po = out + POT_OFF + (size_t)row * NS;
#pragma unroll
      for (int i = 0; i < 6; ++i)
        *(float4*)(po + i * 4) = make_float4(acc[4*i], acc[4*i+1], acc[4*i+2], acc[4*i+3]);
    }
  }

  if (blockIdx.x == 0 && tid < BB) out[LENS_OFF + tid] = (float)TT;
  if (blockIdx.x == 1) {
    for (int i = tid; i < NS * NS; i += 256) out[TRANS_OFF + i] = trans[i];
  }
}

__device__ __forceinline__ float m3(float a, float b, float c) {
  return fmaxf(fmaxf(a, b), c);   // clang fuses to v_max3_f32
}

// DPP row rotate (within 16-lane rows); direction handled by runtime probe.
#define RORI(dst, src, J) \
  dst = __builtin_amdgcn_mov_dpp((src), 0x120 + (J), 0xF, 0xF, true)

// ---------------------------------------------------------------------------
// Kernel 2 (fused): scan + bp + backtrace, one block per batch, 1024 threads.
// Scan: VALU-only cross-lane (permlane32/16_swap + DPP row_ror), ~150cy/step
// (r4 measured). THIS ROUND: bp-build restructured from DS-bound (48 scalar
// ds_read_b32 per (t,n) item ~45us) to DS-light: n fixed per thread (42
// groups of 24 lanes sharing t), trans column preloaded in 24 regs, alpha
// row read as 6 same-addr-broadcast ds_read_b128 (rows are 96B = 6 float4,
// 16B-aligned). DS ops/item 48 -> 7. Same m-order/arithmetic -> bit-exact.
// ---------------------------------------------------------------------------
__global__ __launch_bounds__(1024) void viterbi_fused(
    const float* __restrict__ pot, const float* __restrict__ trans,
    float* __restrict__ out_dec)
{
  __shared__ float ps[(TT + 8) * NS];     // pot rows, overwritten by alpha
  __shared__ unsigned char bl[TT * NS];   // backpointers
  __shared__ float tl[NS * NS];           // trans
  __shared__ int H[32][NS];
  __shared__ int e[32];

  const int b = blockIdx.x, tid = threadIdx.x;

  // ---- stage pot[b] + trans ----
  {
    const float4* src = (const float4*)(pot + (size_t)b * TT * NS);
    float4* dst = (float4*)ps;
#pragma unroll
    for (int i = 0; i < 6; ++i) dst[tid + i * 1024] = src[tid + i * 1024];
    if (tid < NS * NS) tl[tid] = trans[tid];
  }
  __syncthreads();

  // ---- forward scan: wave 0 only (unchanged from r4) ----
  if (tid < 64) {
    const int r = tid >> 4;                // lane row 0..3
    const int c = tid & 15;                // lane col 0..15
    const int g = r >> 1;                  // m-half 0/1
    const int n = 16 * (r & 1) + c;        // tag (valid if < 24)
    const int nm = (n < NS) ? n : (NS - 1);
    const bool wr = (n < NS) && (g == 0);  // unique alpha writers

    // runtime probe: colv[j] = source column of DPP slot j (direction-proof)
    int colv[16];
    colv[0] = c;
    RORI(colv[1],  c, 1);  RORI(colv[2],  c, 2);  RORI(colv[3],  c, 3);
    RORI(colv[4],  c, 4);  RORI(colv[5],  c, 5);  RORI(colv[6],  c, 6);
    RORI(colv[7],  c, 7);  RORI(colv[8],  c, 8);  RORI(colv[9],  c, 9);
    RORI(colv[10], c, 10); RORI(colv[11], c, 11); RORI(colv[12], c, 12);
    RORI(colv[13], c, 13); RORI(colv[14], c, 14); RORI(colv[15], c, 15);

    // runtime probe: which permlane16_swap result holds alpha[16g + c]
    bool selx;
    {
      auto nr = __builtin_amdgcn_permlane16_swap(n, n, false, false);
      selx = (nr[0] == 16 * g + c);
    }

    // per-lane trans constants: slot j pairs with alpha[16g + colv[j]]
    float tcr[16];
#pragma unroll
    for (int j = 0; j < 16; ++j) {
      const int m = 16 * g + colv[j];
      tcr[j] = (m < NS) ? tl[m * NS + nm] : -__builtin_inff();
    }

    // init: slot j holds alpha0[16g + colv[j]] (alpha0 = pot row 0)
    float ar[16];
#pragma unroll
    for (int j = 0; j < 16; ++j) {
      const int m = 16 * g + colv[j];
      ar[j] = ps[(m < NS) ? m : (NS - 1)];
    }

    float pv[8];                           // pot prefetch ring (off-chain)
#pragma unroll
    for (int u = 0; u < 8; ++u) pv[u] = ps[(1 + u) * NS + nm];

    auto step = [&](int tt, float potv) {
      float sc[16];
#pragma unroll
      for (int j = 0; j < 16; ++j) sc[j] = ar[j] + tcr[j];
      float u0 = m3(sc[0],  sc[1],  sc[2]);
      float u1 = m3(sc[3],  sc[4],  sc[5]);
      float u2 = m3(sc[6],  sc[7],  sc[8]);
      float u3 = m3(sc[9],  sc[10], sc[11]);
      float u4 = m3(sc[12], sc[13], sc[14]);
      float pm = fmaxf(m3(u0, u1, u2), m3(u3, u4, sc[15]));   // half-max
      // cross-half combine: one permlane32_swap, results = {own, lane^32}
      auto pr = __builtin_amdgcn_permlane32_swap(
          __float_as_int(pm), __float_as_int(pm), false, false);
      float al = fmaxf(__int_as_float(pr[0]), __int_as_float(pr[1])) + potv;
      if (wr) ps[tt * NS + n] = al;        // off-chain, for bp-build
      // fetch row-partner's alpha; select the half this lane reduces
      auto qr = __builtin_amdgcn_permlane16_swap(
          __float_as_int(al), __float_as_int(al), false, false);
      int asel = selx ? qr[0] : qr[1];     // alpha[16g + c]
      ar[0] = __int_as_float(asel);
      int d1, d2, d3, d4, d5, d6, d7, d8, d9, d10, d11, d12, d13, d14, d15;
      RORI(d1,  asel, 1);  ar[1]  = __int_as_float(d1);
      RORI(d2,  asel, 2);  ar[2]  = __int_as_float(d2);
      RORI(d3,  asel, 3);  ar[3]  = __int_as_float(d3);
      RORI(d4,  asel, 4);  ar[4]  = __int_as_float(d4);
      RORI(d5,  asel, 5);  ar[5]  = __int_as_float(d5);
      RORI(d6,  asel, 6);  ar[6]  = __int_as_float(d6);
      RORI(d7,  asel, 7);  ar[7]  = __int_as_float(d7);
      RORI(d8,  asel, 8);  ar[8]  = __int_as_float(d8);
      RORI(d9,  asel, 9);  ar[9]  = __int_as_float(d9);
      RORI(d10, asel, 10); ar[10] = __int_as_float(d10);
      RORI(d11, asel, 11); ar[11] = __int_as_float(d11);
      RORI(d12, asel, 12); ar[12] = __int_as_float(d12);
      RORI(d13, asel, 13); ar[13] = __int_as_float(d13);
      RORI(d14, asel, 14); ar[14] = __int_as_float(d14);
      RORI(d15, asel, 15); ar[15] = __int_as_float(d15);
    };

    for (int t = 1; t + 7 <= TT - 1; t += 8) {
#pragma unroll
      for (int u = 0; u < 8; ++u) {
        const int tt = t + u;
        const float potv = pv[u];
        pv[u] = ps[(tt + 8) * NS + nm];    // 8 ahead of overwrite frontier
        step(tt, potv);
      }
    }
#pragma unroll
    for (int u = 0; u < 7; ++u) step(1017 + u, pv[u]);
  }
  __syncthreads();

  // ---- bp build: n-per-thread, tl column in regs, b128 row broadcast ----
  if (tid < 1008) {                        // 42 groups x 24 lanes
    const int grp = tid / 24;
    const int n   = tid - grp * 24;
    float tlc[NS];
#pragma unroll
    for (int m = 0; m < NS; ++m) tlc[m] = tl[m * NS + n];
    for (int t = 1 + grp; t <= TT - 1; t += 42) {
      const float4* rr = (const float4*)&ps[(t - 1) * NS];  // 96B row, aligned
      float ar[NS];
#pragma unroll
      for (int i = 0; i < 6; ++i) {
        float4 v = rr[i];
        ar[4*i] = v.x; ar[4*i+1] = v.y; ar[4*i+2] = v.z; ar[4*i+3] = v.w;
      }
      float best = ar[0] + tlc[0];
      int bi = 0;
#pragma unroll
      for (int m = 1; m < NS; ++m) {
        float s = ar[m] + tlc[m];
        bool gg = s > best;
        bi = gg ? m : bi;
        best = gg ? s : best;
      }
      bl[t * NS + n] = (unsigned char)bi;
    }
  }
  __syncthreads();

  // ---- backtrace: chunk composition (C=32) ----
  if (tid < 32 * NS) {
    const int c2 = tid / NS, s = tid % NS;
    int a2 = s;
    int tlo = c2 * 32; if (tlo < 1) tlo = 1;
    for (int t = c2 * 32 + 31; t >= tlo; --t) a2 = bl[t * NS + a2];
    H[c2][s] = a2;
  }
  __syncthreads();

  if (tid == 0) {
    const float* ar = &ps[(TT - 1) * NS];
    float best = ar[0]; int bi = 0;
#pragma unroll
    for (int nn = 1; nn < NS; ++nn) {
      float v = ar[nn];
      if (v > best) { best = v; bi = nn; }
    }
    int tag = bi;
    e[31] = tag;
    for (int c2 = 31; c2 >= 1; --c2) { tag = H[c2][tag]; e[c2 - 1] = tag; }
  }
  __syncthreads();

  if (tid < 32) {
    const int c2 = tid;
    int tag = e[c2];
    float* od = out_dec + (size_t)b * TT;
    od[c2 * 32 + 31] = (float)tag;
    for (int t = c2 * 32 + 30; t >= c2 * 32; --t) {
      tag = bl[(t + 1) * NS + tag];
      od[t] = (float)tag;
    }
  }
}

// ---------------------------------------------------------------------------
extern "C" void kernel_launch(void* const* d_in, const int* in_sizes, int n_in,
                              void* d_out, int out_size, void* d_ws, size_t ws_size,
                              hipStream_t stream)
{
  const float* x     = (const float*)d_in[0];
  const float* W     = (const float*)d_in[1];
  const float* bias  = (const float*)d_in[2];
  const float* trans = (const float*)d_in[3];
  const float* lb    = (const float*)d_in[4];
  const float* rb    = (const float*)d_in[5];
  float* out = (float*)d_out;

  gemm_pot<<<512, 256, 0, stream>>>(x, W, bias, trans, lb, rb, out);
  viterbi_fused<<<BB, 1024, 0, stream>>>(out + POT_OFF, trans, out);
}

// Round 6
// 321.585 us; speedup vs baseline: 1.7347x; 1.0004x over previous
//
#include <hip/hip_runtime.h>
#include <hip/hip_bf16.h>

#define BB 64
#define TT 1024
#define DD 512
#define NS 24

#define POT_OFF   65536
#define LENS_OFF  1638400
#define TRANS_OFF 1638464

// ---------------------------------------------------------------------------
// Kernel 1: pot = x @ W + b (+ boundary adds).  (byte-identical to r5)
// ---------------------------------------------------------------------------
__global__ __launch_bounds__(256) void gemm_pot(
    const float* __restrict__ x, const float* __restrict__ W,
    const float* __restrict__ bias, const float* __restrict__ trans,
    const float* __restrict__ lb, const float* __restrict__ rb,
    float* __restrict__ out)
{
  __shared__ float wl[DD * NS];              // 49,152 B: W, then partials
  const int tid = threadIdx.x;
  const int l   = tid & 63;
  const int q   = tid >> 6;                  // K-quarter
  const int row0 = blockIdx.x * 128 + l;     // this thread's two rows
  const int row1 = row0 + 64;

  // stage W: 12288 floats = 256 threads x 12 float4, coalesced
  {
    const float4* Ws = (const float4*)W;
    float4* Wd = (float4*)wl;
#pragma unroll
    for (int i = 0; i < 12; ++i) Wd[tid + i * 256] = Ws[tid + i * 256];
  }
  __syncthreads();

  const float4* xp0 = (const float4*)(x + (size_t)row0 * DD + q * 128);
  const float4* xp1 = (const float4*)(x + (size_t)row1 * DD + q * 128);

  float acc0[NS], acc1[NS];
#pragma unroll
  for (int nn = 0; nn < NS; ++nn) { acc0[nn] = 0.f; acc1[nn] = 0.f; }

  float4 buf0[4], buf1[4];
#pragma unroll
  for (int i = 0; i < 4; ++i) { buf0[i] = xp0[i]; buf1[i] = xp1[i]; }

#pragma unroll
  for (int f = 0; f < 32; ++f) {             // 32 float4 = 128 k per quarter
    float4 v0 = buf0[f & 3];
    float4 v1 = buf1[f & 3];
    if (f + 4 < 32) { buf0[f & 3] = xp0[f + 4]; buf1[f & 3] = xp1[f + 4]; }
    const float xj0[4] = {v0.x, v0.y, v0.z, v0.w};
    const float xj1[4] = {v1.x, v1.y, v1.z, v1.w};
#pragma unroll
    for (int j = 0; j < 4; ++j) {
      const int k = q * 128 + f * 4 + j;
      const float4* wr = (const float4*)&wl[k * NS];   // same addr all lanes
      float4 w0 = wr[0], w1 = wr[1], w2 = wr[2], w3 = wr[3], w4 = wr[4], w5 = wr[5];
      const float wv[NS] = {w0.x,w0.y,w0.z,w0.w, w1.x,w1.y,w1.z,w1.w,
                            w2.x,w2.y,w2.z,w2.w, w3.x,w3.y,w3.z,w3.w,
                            w4.x,w4.y,w4.z,w4.w, w5.x,w5.y,w5.z,w5.w};
      const float xv0 = xj0[j];
      const float xv1 = xj1[j];
#pragma unroll
      for (int nn = 0; nn < NS; ++nn) {
        acc0[nn] = fmaf(xv0, wv[nn], acc0[nn]);
        acc1[nn] = fmaf(xv1, wv[nn], acc1[nn]);
      }
    }
  }

  // reduce the 4 K-quarter partials through W's (now dead) LDS region
  __syncthreads();
  if (q != 0) {
#pragma unroll
    for (int nn = 0; nn < NS; ++nn) {
      wl[((q - 1) * 128 + l)      * 25 + nn] = acc0[nn];
      wl[((q - 1) * 128 + 64 + l) * 25 + nn] = acc1[nn];
    }
  }
  __syncthreads();
  if (q == 0) {
#pragma unroll
    for (int rr = 0; rr < 2; ++rr) {
      float* acc = rr ? acc1 : acc0;
      const int row = rr ? row1 : row0;
      const int slot = rr ? (64 + l) : l;
      const int t = row & (TT - 1);
#pragma unroll
      for (int nn = 0; nn < NS; ++nn)
        acc[nn] += wl[(0 * 128 + slot) * 25 + nn] + wl[(1 * 128 + slot) * 25 + nn]
                 + wl[(2 * 128 + slot) * 25 + nn] + bias[nn];
      if (t == 0) {
#pragma unroll
        for (int nn = 0; nn < NS; ++nn) acc[nn] += lb[nn];
      }
      if (t == TT - 1) {
#pragma unroll
        for (int nn = 0; nn < NS; ++nn) acc[nn] += rb[nn];
      }
      float* po = out + POT_OFF + (size_t)row * NS;
#pragma unroll
      for (int i = 0; i < 6; ++i)
        *(float4*)(po + i * 4) = make_float4(acc[4*i], acc[4*i+1], acc[4*i+2], acc[4*i+3]);
    }
  }

  if (blockIdx.x == 0 && tid < BB) out[LENS_OFF + tid] = (float)TT;
  if (blockIdx.x == 1) {
    for (int i = tid; i < NS * NS; i += 256) out[TRANS_OFF + i] = trans[i];
  }
}

__device__ __forceinline__ float m3(float a, float b, float c) {
  return fmaxf(fmaxf(a, b), c);   // clang fuses to v_max3_f32
}

// DPP row rotate (within 16-lane rows); direction handled by runtime probe.
#define RORI(dst, src, J) \
  dst = __builtin_amdgcn_mov_dpp((src), 0x120 + (J), 0xF, 0xF, true)

// ---------------------------------------------------------------------------
// Kernel 2 (fused): scan + bp + backtrace, one block per batch, 1024 threads.
// THIS ROUND: (1) no pot staging — scan reads pot straight from global via
// an 8-deep prefetch ring (off-chain; ~1700cy slack covers L2/L3 latency);
// ps is now an ALPHA-ONLY buffer. (2) alpha store is UNCONDITIONAL: lane
// pairs (l, l^32) compute identical al for the same n; lanes with n>=24
// write garbage into row t+1's first 8 slots, which the next step's writers
// overwrite in wave program order (DS is in-order per wave; +8 float slack
// absorbs step 1023). Kills the per-step exec-mask dance. Scan arithmetic,
// permlane/DPP redistribution, bp-build, backtrace: unchanged (bit-exact).
// ---------------------------------------------------------------------------
__global__ __launch_bounds__(1024) void viterbi_fused(
    const float* __restrict__ pot, const float* __restrict__ trans,
    float* __restrict__ out_dec)
{
  __shared__ float ps[TT * NS + 8];       // alpha rows 0..1023 (+ tail slack)
  __shared__ unsigned char bl[TT * NS];   // backpointers
  __shared__ float tl[NS * NS];           // trans (for bp-build)
  __shared__ int H[32][NS];
  __shared__ int e[32];

  const int b = blockIdx.x, tid = threadIdx.x;

  // stage trans for bp-build (no barrier needed before scan: scan reads
  // trans/pot from global; barrier after scan orders tl for bp waves)
  if (tid < NS * NS) tl[tid] = trans[tid];

  // ---- forward scan: wave 0 only ----
  if (tid < 64) {
    const int r = tid >> 4;                // lane row 0..3
    const int c = tid & 15;                // lane col 0..15
    const int g = r >> 1;                  // m-half 0/1
    const int n = 16 * (r & 1) + c;        // tag slot (valid if < 24)
    const int nm = (n < NS) ? n : (NS - 1);

    const float* gp = pot + (size_t)b * TT * NS;   // this batch's pot

    // runtime probe: colv[j] = source column of DPP slot j (direction-proof)
    int colv[16];
    colv[0] = c;
    RORI(colv[1],  c, 1);  RORI(colv[2],  c, 2);  RORI(colv[3],  c, 3);
    RORI(colv[4],  c, 4);  RORI(colv[5],  c, 5);  RORI(colv[6],  c, 6);
    RORI(colv[7],  c, 7);  RORI(colv[8],  c, 8);  RORI(colv[9],  c, 9);
    RORI(colv[10], c, 10); RORI(colv[11], c, 11); RORI(colv[12], c, 12);
    RORI(colv[13], c, 13); RORI(colv[14], c, 14); RORI(colv[15], c, 15);

    // runtime probe: which permlane16_swap result holds alpha[16g + c]
    bool selx;
    {
      auto nr = __builtin_amdgcn_permlane16_swap(n, n, false, false);
      selx = (nr[0] == 16 * g + c);
    }

    // per-lane trans constants from GLOBAL: slot j pairs alpha[16g+colv[j]]
    float tcr[16];
#pragma unroll
    for (int j = 0; j < 16; ++j) {
      const int m = 16 * g + colv[j];
      tcr[j] = (m < NS) ? trans[m * NS + nm] : -__builtin_inff();
    }

    // init: slot j holds alpha0[16g + colv[j]] (alpha0 = pot row 0, global)
    float ar[16];
#pragma unroll
    for (int j = 0; j < 16; ++j) {
      const int m = 16 * g + colv[j];
      ar[j] = gp[(m < NS) ? m : (NS - 1)];
    }

    // write alpha row 0 into LDS for bp-build (unconditional; n>=24 garbage
    // lands in row 1 slots, overwritten by step 1 in program order)
    ps[n] = gp[nm];

    float pv[8];                           // pot prefetch ring (global, off-chain)
#pragma unroll
    for (int u = 0; u < 8; ++u) pv[u] = gp[(1 + u) * NS + nm];

    auto step = [&](int tt, float potv) {
      float sc[16];
#pragma unroll
      for (int j = 0; j < 16; ++j) sc[j] = ar[j] + tcr[j];
      float u0 = m3(sc[0],  sc[1],  sc[2]);
      float u1 = m3(sc[3],  sc[4],  sc[5]);
      float u2 = m3(sc[6],  sc[7],  sc[8]);
      float u3 = m3(sc[9],  sc[10], sc[11]);
      float u4 = m3(sc[12], sc[13], sc[14]);
      float pm = fmaxf(m3(u0, u1, u2), m3(u3, u4, sc[15]));   // half-max
      // cross-half combine: one permlane32_swap, results = {own, lane^32}
      auto pr = __builtin_amdgcn_permlane32_swap(
          __float_as_int(pm), __float_as_int(pm), false, false);
      float al = fmaxf(__int_as_float(pr[0]), __int_as_float(pr[1])) + potv;
      ps[tt * NS + n] = al;                // unconditional (see header note)
      // fetch row-partner's alpha; select the half this lane reduces
      auto qr = __builtin_amdgcn_permlane16_swap(
          __float_as_int(al), __float_as_int(al), false, false);
      int asel = selx ? qr[0] : qr[1];     // alpha[16g + c]
      ar[0] = __int_as_float(asel);
      int d1, d2, d3, d4, d5, d6, d7, d8, d9, d10, d11, d12, d13, d14, d15;
      RORI(d1,  asel, 1);  ar[1]  = __int_as_float(d1);
      RORI(d2,  asel, 2);  ar[2]  = __int_as_float(d2);
      RORI(d3,  asel, 3);  ar[3]  = __int_as_float(d3);
      RORI(d4,  asel, 4);  ar[4]  = __int_as_float(d4);
      RORI(d5,  asel, 5);  ar[5]  = __int_as_float(d5);
      RORI(d6,  asel, 6);  ar[6]  = __int_as_float(d6);
      RORI(d7,  asel, 7);  ar[7]  = __int_as_float(d7);
      RORI(d8,  asel, 8);  ar[8]  = __int_as_float(d8);
      RORI(d9,  asel, 9);  ar[9]  = __int_as_float(d9);
      RORI(d10, asel, 10); ar[10] = __int_as_float(d10);
      RORI(d11, asel, 11); ar[11] = __int_as_float(d11);
      RORI(d12, asel, 12); ar[12] = __int_as_float(d12);
      RORI(d13, asel, 13); ar[13] = __int_as_float(d13);
      RORI(d14, asel, 14); ar[14] = __int_as_float(d14);
      RORI(d15, asel, 15); ar[15] = __int_as_float(d15);
    };

    for (int t = 1; t + 7 <= TT - 1; t += 8) {
#pragma unroll
      for (int u = 0; u < 8; ++u) {
        const int tt = t + u;
        const float potv = pv[u];
        pv[u] = gp[(tt + 8) * NS + nm];    // prefetch (tt+8<=1024: last one
        step(tt, potv);                    //  reads past row 1023 into the
      }                                    //  adjacent out-buffer region —
    }                                      //  valid memory, never consumed)
#pragma unroll
    for (int u = 0; u < 7; ++u) step(1017 + u, pv[u]);
  }
  __syncthreads();

  // ---- bp build: n-per-thread, tl column in regs, b128 row broadcast ----
  if (tid < 1008) {                        // 42 groups x 24 lanes
    const int grp = tid / 24;
    const int n   = tid - grp * 24;
    float tlc[NS];
#pragma unroll
    for (int m = 0; m < NS; ++m) tlc[m] = tl[m * NS + n];
    for (int t = 1 + grp; t <= TT - 1; t += 42) {
      const float4* rr = (const float4*)&ps[(t - 1) * NS];  // 96B row, aligned
      float ar[NS];
#pragma unroll
      for (int i = 0; i < 6; ++i) {
        float4 v = rr[i];
        ar[4*i] = v.x; ar[4*i+1] = v.y; ar[4*i+2] = v.z; ar[4*i+3] = v.w;
      }
      float best = ar[0] + tlc[0];
      int bi = 0;
#pragma unroll
      for (int m = 1; m < NS; ++m) {
        float s = ar[m] + tlc[m];
        bool gg = s > best;
        bi = gg ? m : bi;
        best = gg ? s : best;
      }
      bl[t * NS + n] = (unsigned char)bi;
    }
  }
  __syncthreads();

  // ---- backtrace: chunk composition (C=32) ----
  if (tid < 32 * NS) {
    const int c2 = tid / NS, s = tid % NS;
    int a2 = s;
    int tlo = c2 * 32; if (tlo < 1) tlo = 1;
    for (int t = c2 * 32 + 31; t >= tlo; --t) a2 = bl[t * NS + a2];
    H[c2][s] = a2;
  }
  __syncthreads();

  if (tid == 0) {
    const float* ar = &ps[(TT - 1) * NS];
    float best = ar[0]; int bi = 0;
#pragma unroll
    for (int nn = 1; nn < NS; ++nn) {
      float v = ar[nn];
      if (v > best) { best = v; bi = nn; }
    }
    int tag = bi;
    e[31] = tag;
    for (int c2 = 31; c2 >= 1; --c2) { tag = H[c2][tag]; e[c2 - 1] = tag; }
  }
  __syncthreads();

  if (tid < 32) {
    const int c2 = tid;
    int tag = e[c2];
    float* od = out_dec + (size_t)b * TT;
    od[c2 * 32 + 31] = (float)tag;
    for (int t = c2 * 32 + 30; t >= c2 * 32; --t) {
      tag = bl[(t + 1) * NS + tag];
      od[t] = (float)tag;
    }
  }
}

// ---------------------------------------------------------------------------
extern "C" void kernel_launch(void* const* d_in, const int* in_sizes, int n_in,
                              void* d_out, int out_size, void* d_ws, size_t ws_size,
                              hipStream_t stream)
{
  const float* x     = (const float*)d_in[0];
  const float* W     = (const float*)d_in[1];
  const float* bias  = (const float*)d_in[2];
  const float* trans = (const float*)d_in[3];
  const float* lb    = (const float*)d_in[4];
  const float* rb    = (const float*)d_in[5];
  float* out = (float*)d_out;

  gemm_pot<<<512, 256, 0, stream>>>(x, W, bias, trans, lb, rb, out);
  viterbi_fused<<<BB, 1024, 0, stream>>>(out + POT_OFF, trans, out);
}

// Round 8
// 317.372 us; speedup vs baseline: 1.7578x; 1.0133x over previous
//
#include <hip/hip_runtime.h>
#include <hip/hip_bf16.h>

#define BB 64
#define TT 1024
#define DD 512
#define NS 24

#define POT_OFF   65536
#define LENS_OFF  1638400
#define TRANS_OFF 1638464

// ---------------------------------------------------------------------------
// Kernel 1: pot = x @ W + b (+ boundary adds).  (byte-identical to r5/r6)
// ---------------------------------------------------------------------------
__global__ __launch_bounds__(256) void gemm_pot(
    const float* __restrict__ x, const float* __restrict__ W,
    const float* __restrict__ bias, const float* __restrict__ trans,
    const float* __restrict__ lb, const float* __restrict__ rb,
    float* __restrict__ out)
{
  __shared__ float wl[DD * NS];              // 49,152 B: W, then partials
  const int tid = threadIdx.x;
  const int l   = tid & 63;
  const int q   = tid >> 6;                  // K-quarter
  const int row0 = blockIdx.x * 128 + l;     // this thread's two rows
  const int row1 = row0 + 64;

  // stage W: 12288 floats = 256 threads x 12 float4, coalesced
  {
    const float4* Ws = (const float4*)W;
    float4* Wd = (float4*)wl;
#pragma unroll
    for (int i = 0; i < 12; ++i) Wd[tid + i * 256] = Ws[tid + i * 256];
  }
  __syncthreads();

  const float4* xp0 = (const float4*)(x + (size_t)row0 * DD + q * 128);
  const float4* xp1 = (const float4*)(x + (size_t)row1 * DD + q * 128);

  float acc0[NS], acc1[NS];
#pragma unroll
  for (int nn = 0; nn < NS; ++nn) { acc0[nn] = 0.f; acc1[nn] = 0.f; }

  float4 buf0[4], buf1[4];
#pragma unroll
  for (int i = 0; i < 4; ++i) { buf0[i] = xp0[i]; buf1[i] = xp1[i]; }

#pragma unroll
  for (int f = 0; f < 32; ++f) {             // 32 float4 = 128 k per quarter
    float4 v0 = buf0[f & 3];
    float4 v1 = buf1[f & 3];
    if (f + 4 < 32) { buf0[f & 3] = xp0[f + 4]; buf1[f & 3] = xp1[f + 4]; }
    const float xj0[4] = {v0.x, v0.y, v0.z, v0.w};
    const float xj1[4] = {v1.x, v1.y, v1.z, v1.w};
#pragma unroll
    for (int j = 0; j < 4; ++j) {
      const int k = q * 128 + f * 4 + j;
      const float4* wr = (const float4*)&wl[k * NS];   // same addr all lanes
      float4 w0 = wr[0], w1 = wr[1], w2 = wr[2], w3 = wr[3], w4 = wr[4], w5 = wr[5];
      const float wv[NS] = {w0.x,w0.y,w0.z,w0.w, w1.x,w1.y,w1.z,w1.w,
                            w2.x,w2.y,w2.z,w2.w, w3.x,w3.y,w3.z,w3.w,
                            w4.x,w4.y,w4.z,w4.w, w5.x,w5.y,w5.z,w5.w};
      const float xv0 = xj0[j];
      const float xv1 = xj1[j];
#pragma unroll
      for (int nn = 0; nn < NS; ++nn) {
        acc0[nn] = fmaf(xv0, wv[nn], acc0[nn]);
        acc1[nn] = fmaf(xv1, wv[nn], acc1[nn]);
      }
    }
  }

  // reduce the 4 K-quarter partials through W's (now dead) LDS region
  __syncthreads();
  if (q != 0) {
#pragma unroll
    for (int nn = 0; nn < NS; ++nn) {
      wl[((q - 1) * 128 + l)      * 25 + nn] = acc0[nn];
      wl[((q - 1) * 128 + 64 + l) * 25 + nn] = acc1[nn];
    }
  }
  __syncthreads();
  if (q == 0) {
#pragma unroll
    for (int rr = 0; rr < 2; ++rr) {
      float* acc = rr ? acc1 : acc0;
      const int row = rr ? row1 : row0;
      const int slot = rr ? (64 + l) : l;
      const int t = row & (TT - 1);
#pragma unroll
      for (int nn = 0; nn < NS; ++nn)
        acc[nn] += wl[(0 * 128 + slot) * 25 + nn] + wl[(1 * 128 + slot) * 25 + nn]
                 + wl[(2 * 128 + slot) * 25 + nn] + bias[nn];
      if (t == 0) {
#pragma unroll
        for (int nn = 0; nn < NS; ++nn) acc[nn] += lb[nn];
      }
      if (t == TT - 1) {
#pragma unroll
        for (int nn = 0; nn < NS; ++nn) acc[nn] += rb[nn];
      }
      float* po = out + POT_OFF + (size_t)row * NS;
#pragma unroll
      for (int i = 0; i < 6; ++i)
        *(float4*)(po + i * 4) = make_float4(acc[4*i], acc[4*i+1], acc[4*i+2], acc[4*i+3]);
    }
  }

  if (blockIdx.x == 0 && tid < BB) out[LENS_OFF + tid] = (float)TT;
  if (blockIdx.x == 1) {
    for (int i = tid; i < NS * NS; i += 256) out[TRANS_OFF + i] = trans[i];
  }
}

__device__ __forceinline__ float m3(float a, float b, float c) {
  return fmaxf(fmaxf(a, b), c);   // clang fuses to v_max3_f32
}

// DPP row rotate (within 16-lane rows); direction handled by runtime probe.
#define RORI(dst, src, J) \
  dst = __builtin_amdgcn_mov_dpp((src), 0x120 + (J), 0xF, 0xF, true)

// ---------------------------------------------------------------------------
// Kernel 2 (fused): scan + bp + backtrace, one block per batch, 1024 threads.
// bp-build CHASES the scan concurrently. Wave 0 scans (VALU-only
// permlane/DPP step, unchanged bit-exact) at s_setprio(1) and publishes an
// LDS progress counter every 8 steps (in-order DS per wave => prog>=ta
// guarantees alpha rows <=ta final, incl. dup-lane stomp-at-R-1/fix-at-R).
// Waves 1..15 each own a contiguous 69-row t-chunk: spin on prog (s_sleep,
// compiler-fence only -- no lgkmcnt stall for wave 0), then compute bp for
// 2 rows/iter (lanes 0..47 = 2 x 24 tags, trans column in regs, alpha row
// via same-addr b128 broadcast). Same score order/strict-> semantics =>
// bl bit-exact. bp cost (~8-12us) hides under the ~100us scan.
// Release proof: wave 0's scan is a fixed 1023-trip loop; final publish
// prog=1023 >= any chaser's ta; all 16 waves co-resident (one workgroup).
// ---------------------------------------------------------------------------
__global__ __launch_bounds__(1024) void viterbi_fused(
    const float* __restrict__ pot, const float* __restrict__ trans,
    float* __restrict__ out_dec)
{
  __shared__ float ps[TT * NS + 8];       // alpha rows 0..1023 (+ tail slack)
  __shared__ unsigned char bl[TT * NS];   // backpointers
  __shared__ float tl[NS * NS];           // trans (for bp-build)
  __shared__ int H[32][NS];
  __shared__ int e[32];
  __shared__ int prog;                    // scan frontier (last final row)

  const int b = blockIdx.x, tid = threadIdx.x;

  // stage trans for bp-build; init progress; one barrier before both phases
  if (tid < NS * NS) tl[tid] = trans[tid];
  if (tid == 0) *(volatile int*)&prog = 0;
  __syncthreads();

  if (tid < 64) {
    // ---- forward scan: wave 0, priority-boosted ----
    __builtin_amdgcn_s_setprio(1);
    const int r = tid >> 4;                // lane row 0..3
    const int c = tid & 15;                // lane col 0..15
    const int g = r >> 1;                  // m-half 0/1
    const int n = 16 * (r & 1) + c;        // tag slot (valid if < 24)
    const int nm = (n < NS) ? n : (NS - 1);

    const float* gp = pot + (size_t)b * TT * NS;   // this batch's pot

    // runtime probe: colv[j] = source column of DPP slot j (direction-proof)
    int colv[16];
    colv[0] = c;
    RORI(colv[1],  c, 1);  RORI(colv[2],  c, 2);  RORI(colv[3],  c, 3);
    RORI(colv[4],  c, 4);  RORI(colv[5],  c, 5);  RORI(colv[6],  c, 6);
    RORI(colv[7],  c, 7);  RORI(colv[8],  c, 8);  RORI(colv[9],  c, 9);
    RORI(colv[10], c, 10); RORI(colv[11], c, 11); RORI(colv[12], c, 12);
    RORI(colv[13], c, 13); RORI(colv[14], c, 14); RORI(colv[15], c, 15);

    // runtime probe: which permlane16_swap result holds alpha[16g + c]
    bool selx;
    {
      auto nr = __builtin_amdgcn_permlane16_swap(n, n, false, false);
      selx = (nr[0] == 16 * g + c);
    }

    // per-lane trans constants from GLOBAL: slot j pairs alpha[16g+colv[j]]
    float tcr[16];
#pragma unroll
    for (int j = 0; j < 16; ++j) {
      const int m = 16 * g + colv[j];
      tcr[j] = (m < NS) ? trans[m * NS + nm] : -__builtin_inff();
    }

    // init: slot j holds alpha0[16g + colv[j]] (alpha0 = pot row 0, global)
    float ar[16];
#pragma unroll
    for (int j = 0; j < 16; ++j) {
      const int m = 16 * g + colv[j];
      ar[j] = gp[(m < NS) ? m : (NS - 1)];
    }

    // write alpha row 0 into LDS for bp-build (unconditional; n>=24 garbage
    // lands in row 1 slots, overwritten by step 1 in program order)
    ps[n] = gp[nm];

    float pv[8];                           // pot prefetch ring (global, off-chain)
#pragma unroll
    for (int u = 0; u < 8; ++u) pv[u] = gp[(1 + u) * NS + nm];

    auto step = [&](int tt, float potv) {
      float sc[16];
#pragma unroll
      for (int j = 0; j < 16; ++j) sc[j] = ar[j] + tcr[j];
      float u0 = m3(sc[0],  sc[1],  sc[2]);
      float u1 = m3(sc[3],  sc[4],  sc[5]);
      float u2 = m3(sc[6],  sc[7],  sc[8]);
      float u3 = m3(sc[9],  sc[10], sc[11]);
      float u4 = m3(sc[12], sc[13], sc[14]);
      float pm = fmaxf(m3(u0, u1, u2), m3(u3, u4, sc[15]));   // half-max
      // cross-half combine: one permlane32_swap, results = {own, lane^32}
      auto pr = __builtin_amdgcn_permlane32_swap(
          __float_as_int(pm), __float_as_int(pm), false, false);
      float al = fmaxf(__int_as_float(pr[0]), __int_as_float(pr[1])) + potv;
      ps[tt * NS + n] = al;                // unconditional (see header note)
      // fetch row-partner's alpha; select the half this lane reduces
      auto qr = __builtin_amdgcn_permlane16_swap(
          __float_as_int(al), __float_as_int(al), false, false);
      int asel = selx ? qr[0] : qr[1];     // alpha[16g + c]
      ar[0] = __int_as_float(asel);
      int d1, d2, d3, d4, d5, d6, d7, d8, d9, d10, d11, d12, d13, d14, d15;
      RORI(d1,  asel, 1);  ar[1]  = __int_as_float(d1);
      RORI(d2,  asel, 2);  ar[2]  = __int_as_float(d2);
      RORI(d3,  asel, 3);  ar[3]  = __int_as_float(d3);
      RORI(d4,  asel, 4);  ar[4]  = __int_as_float(d4);
      RORI(d5,  asel, 5);  ar[5]  = __int_as_float(d5);
      RORI(d6,  asel, 6);  ar[6]  = __int_as_float(d6);
      RORI(d7,  asel, 7);  ar[7]  = __int_as_float(d7);
      RORI(d8,  asel, 8);  ar[8]  = __int_as_float(d8);
      RORI(d9,  asel, 9);  ar[9]  = __int_as_float(d9);
      RORI(d10, asel, 10); ar[10] = __int_as_float(d10);
      RORI(d11, asel, 11); ar[11] = __int_as_float(d11);
      RORI(d12, asel, 12); ar[12] = __int_as_float(d12);
      RORI(d13, asel, 13); ar[13] = __int_as_float(d13);
      RORI(d14, asel, 14); ar[14] = __int_as_float(d14);
      RORI(d15, asel, 15); ar[15] = __int_as_float(d15);
    };

    for (int t = 1; t + 7 <= TT - 1; t += 8) {
#pragma unroll
      for (int u = 0; u < 8; ++u) {
        const int tt = t + u;
        const float potv = pv[u];
        pv[u] = gp[(tt + 8) * NS + nm];    // prefetch (last reads into the
        step(tt, potv);                    //  adjacent out-region: valid mem,
      }                                    //  never consumed)
      asm volatile("" ::: "memory");       // order alpha stores before prog
      *(volatile int*)&prog = t + 7;       // publish frontier (1 DS/8 steps)
    }
#pragma unroll
    for (int u = 0; u < 7; ++u) step(1017 + u, pv[u]);
    asm volatile("" ::: "memory");
    *(volatile int*)&prog = TT - 1;        // final frontier
    __builtin_amdgcn_s_setprio(0);
  } else {
    // ---- bp-build: waves 1..15 chase the scan frontier ----
    const int w  = tid >> 6;               // 1..15
    const int l  = tid & 63;
    const int t0 = 1 + (w - 1) * 69;
    const int tend = (t0 + 68 < TT - 1) ? (t0 + 68) : (TT - 1);
    const int half = (l >= 24) ? 1 : 0;    // second row of the pair
    const int n = (l < 24) ? l : ((l < 48) ? (l - 24) : 0);
    float tlc[NS];
#pragma unroll
    for (int m = 0; m < NS; ++m) tlc[m] = tl[m * NS + n];
    for (int ta = t0; ta <= tend; ta += 2) {
      while (*(volatile int*)&prog < ta) __builtin_amdgcn_s_sleep(1);
      asm volatile("" ::: "memory");       // no hoisting of row reads
      const int tloc = ta + half;
      if (l < 48 && tloc <= tend) {
        const float4* rr = (const float4*)&ps[(tloc - 1) * NS]; // 96B row
        float arr[NS];
#pragma unroll
        for (int i = 0; i < 6; ++i) {
          float4 v = rr[i];
          arr[4*i] = v.x; arr[4*i+1] = v.y; arr[4*i+2] = v.z; arr[4*i+3] = v.w;
        }
        float best = arr[0] + tlc[0];
        int bi = 0;
#pragma unroll
        for (int m = 1; m < NS; ++m) {
          float s = arr[m] + tlc[m];
          bool gg = s > best;
          bi = gg ? m : bi;
          best = gg ? s : best;
        }
        bl[tloc * NS + n] = (unsigned char)bi;
      }
    }
  }
  __syncthreads();

  // ---- backtrace: chunk composition (C=32) ----
  if (tid < 32 * NS) {
    const int c2 = tid / NS, s = tid % NS;
    int a2 = s;
    int tlo = c2 * 32; if (tlo < 1) tlo = 1;
    for (int t = c2 * 32 + 31; t >= tlo; --t) a2 = bl[t * NS + a2];
    H[c2][s] = a2;
  }
  __syncthreads();

  if (tid == 0) {
    const float* ar = &ps[(TT - 1) * NS];
    float best = ar[0]; int bi = 0;
#pragma unroll
    for (int nn = 1; nn < NS; ++nn) {
      float v = ar[nn];
      if (v > best) { best = v; bi = nn; }
    }
    int tag = bi;
    e[31] = tag;
    for (int c2 = 31; c2 >= 1; --c2) { tag = H[c2][tag]; e[c2 - 1] = tag; }
  }
  __syncthreads();

  if (tid < 32) {
    const int c2 = tid;
    int tag = e[c2];
    float* od = out_dec + (size_t)b * TT;
    od[c2 * 32 + 31] = (float)tag;
    for (int t = c2 * 32 + 30; t >= c2 * 32; --t) {
      tag = bl[(t + 1) * NS + tag];
      od[t] = (float)tag;
    }
  }
}

// ---------------------------------------------------------------------------
extern "C" void kernel_launch(void* const* d_in, const int* in_sizes, int n_in,
                              void* d_out, int out_size, void* d_ws, size_t ws_size,
                              hipStream_t stream)
{
  const float* x     = (const float*)d_in[0];
  const float* W     = (const float*)d_in[1];
  const float* bias  = (const float*)d_in[2];
  const float* trans = (const float*)d_in[3];
  const float* lb    = (const float*)d_in[4];
  const float* rb    = (const float*)d_in[5];
  float* out = (float*)d_out;

  gemm_pot<<<512, 256, 0, stream>>>(x, W, bias, trans, lb, rb, out);
  viterbi_fused<<<BB, 1024, 0, stream>>>(out + POT_OFF, trans, out);
}